// Round 1
// baseline (1424.940 us; speedup 1.0000x reference)
//
#include <hip/hip_runtime.h>
#include <math.h>

// Problem: N=65536 rows, K=1024 candidates, D=4.
// out = mean_n( 2*acos( clamp_upper( max_k |dot(x[n,k,:], y[n,0,:])| ) ) )
// w_y (d_in[1]) is unused by the reference. Pure HBM-read-bound (~1 GiB of x).

static constexpr float UPPER_F = 0.9999999f;

template <int KC>
__global__ __launch_bounds__(256, 4) void minarc_k(
    const float4* __restrict__ y4,   // N float4 (y[n,0,:])
    const float4* __restrict__ x4,   // N*KC float4 (x[n,k,:])
    float* __restrict__ out,
    int N, float inv_n)
{
    const int tid        = threadIdx.x;
    const int lane       = tid & 63;
    const int waveInBlk  = tid >> 6;
    const int wavesTotal = (gridDim.x * blockDim.x) >> 6;
    const int wave       = ((blockIdx.x * blockDim.x) >> 6) + waveInBlk;

    float sum = 0.0f;
    for (int n = wave; n < N; n += wavesTotal) {
        const float4 yv = y4[n];                 // same addr across wave -> broadcast
        const float4* __restrict__ xr = x4 + (size_t)n * KC;
        float m = 0.0f;
        #pragma unroll
        for (int j = 0; j < KC / 64; ++j) {      // 16 independent 16B loads in flight
            float4 f = xr[lane + 64 * j];
            float c = fabsf(fmaf(f.x, yv.x,
                           fmaf(f.y, yv.y,
                           fmaf(f.z, yv.z, f.w * yv.w))));
            m = fmaxf(m, c);
        }
        #pragma unroll
        for (int off = 32; off >= 1; off >>= 1)
            m = fmaxf(m, __shfl_xor(m, off, 64));
        if (lane == 0) {
            if (m > UPPER_F) m = 1.0f;           // lower clamp unreachable (m >= 0)
            sum += 2.0f * acosf(m);
        }
    }

    __shared__ float s[4];
    if (lane == 0) s[waveInBlk] = sum;
    __syncthreads();
    if (tid == 0)
        atomicAdd(out, (s[0] + s[1] + s[2] + s[3]) * inv_n);
}

// Generic-K fallback (not used for the bench shape, kept for safety).
__global__ __launch_bounds__(256, 4) void minarc_generic(
    const float4* __restrict__ y4,
    const float4* __restrict__ x4,
    float* __restrict__ out,
    int N, int K, float inv_n)
{
    const int tid        = threadIdx.x;
    const int lane       = tid & 63;
    const int waveInBlk  = tid >> 6;
    const int wavesTotal = (gridDim.x * blockDim.x) >> 6;
    const int wave       = ((blockIdx.x * blockDim.x) >> 6) + waveInBlk;

    float sum = 0.0f;
    for (int n = wave; n < N; n += wavesTotal) {
        const float4 yv = y4[n];
        const float4* __restrict__ xr = x4 + (size_t)n * K;
        float m = 0.0f;
        #pragma unroll 8
        for (int k = lane; k < K; k += 64) {
            float4 f = xr[k];
            float c = fabsf(fmaf(f.x, yv.x,
                           fmaf(f.y, yv.y,
                           fmaf(f.z, yv.z, f.w * yv.w))));
            m = fmaxf(m, c);
        }
        #pragma unroll
        for (int off = 32; off >= 1; off >>= 1)
            m = fmaxf(m, __shfl_xor(m, off, 64));
        if (lane == 0) {
            if (m > UPPER_F) m = 1.0f;
            sum += 2.0f * acosf(m);
        }
    }

    __shared__ float s[4];
    if (lane == 0) s[waveInBlk] = sum;
    __syncthreads();
    if (tid == 0)
        atomicAdd(out, (s[0] + s[1] + s[2] + s[3]) * inv_n);
}

extern "C" void kernel_launch(void* const* d_in, const int* in_sizes, int n_in,
                              void* d_out, int out_size, void* d_ws, size_t ws_size,
                              hipStream_t stream) {
    // setup_inputs order: y (N*1*4), w_y (N*K, unused), x (N*K*4)
    const float4* y4 = (const float4*)d_in[0];
    const float4* x4 = (const float4*)d_in[2];
    float* out = (float*)d_out;

    const int N = in_sizes[0] / 4;            // P=1, D=4
    const int K = in_sizes[2] / (N * 4);
    const float inv_n = 1.0f / (float)N;

    // d_out is poisoned to 0xAA each run; zero it (memset node is graph-legal).
    hipMemsetAsync(d_out, 0, sizeof(float), stream);

    const int blocks = 4096;                  // 4096 waves*4 rows... (16384 waves, 4 rows/wave)
    if (K == 1024) {
        minarc_k<1024><<<blocks, 256, 0, stream>>>(y4, x4, out, N, inv_n);
    } else {
        minarc_generic<<<blocks, 256, 0, stream>>>(y4, x4, out, N, K, inv_n);
    }
}